// Round 8
// baseline (230.590 us; speedup 1.0000x reference)
//
#include <hip/hip_runtime.h>

// cumprod along dim 1 of (ROWS, N) fp32, row-major.
// One wave per row, ALL waves resident (zero block turnover), no barriers.
// Depth-4 LDS pipeline via global_load_lds DMA with exactly-counted vmcnt
// waits; prefetch for tile t+4 is issued AFTER the scan's ds_reads of the
// buffer it reuses (race-free: ds_reads are complete before the wave can
// issue the DMA). Loads stay ~3 tiles ahead; stores get >=4 iterations of
// ack slack before any wait can block on them (vmcnt counts stores; R7's
// vmcnt(8) accidentally drained its own store stream every iteration).
//
// Ledger at iter t's wait (issue order: L(t)[iter t-4, post-scan] ...
// S(t-4)..S(t-1), L(t+1)..L(t+3) interleaved ... WAIT_t):
//   ops younger than L(t) = 2*( min(3, NT-1-t) loads + min(4, t) stores ).

#define N      8192
#define T      256
#define WPB    (T / 64)         // 4 waves per block
#define TILE   512              // elems per tile = 2 KB
#define NT     (N / TILE)       // 16 tiles per row
#define CHK    (TILE / 256)     // 2 chunks (256 elems) per tile
#define DEPTH  4                // pipeline depth (LDS buffers per wave)

typedef float f32x4 __attribute__((ext_vector_type(4)));
typedef const __attribute__((address_space(1))) float glb_f;
typedef __attribute__((address_space(3))) float lds_f;

__device__ __forceinline__ float readlane63(float x) {
    return __builtin_bit_cast(float,
        __builtin_amdgcn_readlane(__builtin_bit_cast(int, x), 63));
}

template<int CTRL, int RM, int BM>
__device__ __forceinline__ float dpp_id1(float x) {
    int r = __builtin_amdgcn_update_dpp(
        __builtin_bit_cast(int, 1.0f), __builtin_bit_cast(int, x),
        CTRL, RM, BM, false);
    return __builtin_bit_cast(float, r);
}

// Wave64 inclusive product-scan, pure VALU (verified rounds 5-7).
__device__ __forceinline__ float wave_scan_mul(float x) {
    x *= dpp_id1<0x111, 0xf, 0xf>(x);   // row_shr:1
    x *= dpp_id1<0x112, 0xf, 0xf>(x);   // row_shr:2
    x *= dpp_id1<0x114, 0xf, 0xf>(x);   // row_shr:4
    x *= dpp_id1<0x118, 0xf, 0xf>(x);   // row_shr:8
    x *= dpp_id1<0x142, 0xa, 0xf>(x);   // row_bcast:15
    x *= dpp_id1<0x143, 0xc, 0xf>(x);   // row_bcast:31
    return x;
}

// Counted vmcnt; vm is compile-time per unrolled iteration -> folds to one asm.
__device__ __forceinline__ void wait_vm(int vm) {
    if      (vm >= 14) asm volatile("s_waitcnt vmcnt(14)" ::: "memory");
    else if (vm == 12) asm volatile("s_waitcnt vmcnt(12)" ::: "memory");
    else if (vm == 10) asm volatile("s_waitcnt vmcnt(10)" ::: "memory");
    else if (vm == 8)  asm volatile("s_waitcnt vmcnt(8)"  ::: "memory");
    else if (vm == 6)  asm volatile("s_waitcnt vmcnt(6)"  ::: "memory");
    else if (vm == 4)  asm volatile("s_waitcnt vmcnt(4)"  ::: "memory");
    else if (vm == 2)  asm volatile("s_waitcnt vmcnt(2)"  ::: "memory");
    else               asm volatile("s_waitcnt vmcnt(0)"  ::: "memory");
}

__global__ __launch_bounds__(T) void cumprod_rows_kernel(
    const float* __restrict__ x, float* __restrict__ out, int n_rows)
{
    __shared__ float lds[WPB][DEPTH][TILE];   // 32 KB -> 5 blocks/CU resident

    const int lane = threadIdx.x & 63;
    const int wid  = threadIdx.x >> 6;
    const int row  = blockIdx.x * WPB + wid;
    if (row >= n_rows) return;               // no barriers -> safe

    const float* __restrict__ xr   = x   + (size_t)row * N;
    float*       __restrict__ outr = out + (size_t)row * N;

    // ---- prologue: DMA tiles 0..3 ----
#pragma unroll
    for (int t = 0; t < DEPTH; ++t)
#pragma unroll
        for (int c = 0; c < CHK; ++c)
            __builtin_amdgcn_global_load_lds(
                (glb_f*)(xr + t * TILE + c * 256 + lane * 4),
                (lds_f*)&lds[wid][t][c * 256], 16, 0, 0);

    float carry = 1.0f;

#pragma unroll
    for (int t = 0; t < NT; ++t) {
        const int b = t % DEPTH;

        // ---- exactly-counted wait: L(t) retired, both pipelines stay full ----
        {
            const int nl = (NT - 1 - t < DEPTH - 1) ? (NT - 1 - t) : (DEPTH - 1);
            const int ns = (t < DEPTH) ? t : DEPTH;
            wait_vm(2 * (nl + ns));
        }
        __builtin_amdgcn_sched_barrier(0);

        // ---- scan tile t from LDS (register DPP machinery) ----
        f32x4 d[CHK];
        float coef[CHK];
#pragma unroll
        for (int c = 0; c < CHK; ++c) {
            d[c] = *reinterpret_cast<const f32x4*>(
                       &lds[wid][b][c * 256 + lane * 4]);
            d[c].y *= d[c].x;
            d[c].z *= d[c].y;
            d[c].w *= d[c].z;
            const float tt = d[c].w;
            const float e  = __shfl_up(tt, 1, 64);
            const float ep = (lane == 0) ? 1.0f : e;
            const float exc = wave_scan_mul(ep);
            coef[c] = carry * exc;
            carry  *= readlane63(exc * tt);
        }
        __builtin_amdgcn_sched_barrier(0);   // ds_reads of buf b complete here

        // ---- refill buffer b with tile t+4 (race-free: reads done) ----
        if (t + DEPTH < NT) {
#pragma unroll
            for (int c = 0; c < CHK; ++c)
                __builtin_amdgcn_global_load_lds(
                    (glb_f*)(xr + (t + DEPTH) * TILE + c * 256 + lane * 4),
                    (lds_f*)&lds[wid][b][c * 256], 16, 0, 0);
        }

        // ---- nontemporal coalesced stores ----
#pragma unroll
        for (int c = 0; c < CHK; ++c) {
            f32x4 o = d[c];
            o.x *= coef[c]; o.y *= coef[c];
            o.z *= coef[c]; o.w *= coef[c];
            __builtin_nontemporal_store(
                o, reinterpret_cast<f32x4*>(outr + t * TILE + c * 256 + lane * 4));
        }
    }
}

extern "C" void kernel_launch(void* const* d_in, const int* in_sizes, int n_in,
                              void* d_out, int out_size, void* d_ws, size_t ws_size,
                              hipStream_t stream)
{
    const float* x   = (const float*)d_in[0];
    float*       out = (float*)d_out;
    const int n_rows = in_sizes[0] / N;                 // 4096
    const int nblk   = (n_rows + WPB - 1) / WPB;        // 1024 (all resident)
    cumprod_rows_kernel<<<nblk, T, 0, stream>>>(x, out, n_rows);
}